// Round 4
// baseline (150.865 us; speedup 1.0000x reference)
//
#include <hip/hip_runtime.h>

#define BATCH 4
#define SEQ   4096
#define CDIM  1024
#define HDIM  64

typedef __attribute__((ext_vector_type(8))) short bf16x8;
typedef __attribute__((ext_vector_type(4))) float f32x4;

// ws layout (in shorts):
//   wt2 [32 k0g][12 p=m*4+hc][64 lane][8]  (bf16, MFMA-fragment order) @ 0
//   q   [16384][64]   (bf16, row-major)   @ Q_OFF
//   k   [16384][64]   (bf16, row-major)   @ K_OFF
//   vt  [4][64][4096] (bf16, transposed)  @ VT_OFF
#define WT_OFF 0
#define Q_OFF  (3 * HDIM * CDIM)
#define K_OFF  (Q_OFF + BATCH * SEQ * HDIM)
#define VT_OFF (K_OFF + BATCH * SEQ * HDIM)

static __device__ __forceinline__ short f2bf(float f) {
  union { float f; unsigned u; } a; a.f = f;
  unsigned r = a.u + 0x7fffu + ((a.u >> 16) & 1u);   // RNE
  return (short)(r >> 16);
}

static __device__ __forceinline__ bf16x8 ld8(const short* p) {
  return *(const bf16x8*)p;
}

// ---------------- kernel 0: W -> bf16, MFMA-fragment order ----------------
__global__ void wcvt_kernel(const float* __restrict__ wq, const float* __restrict__ wk,
                            const float* __restrict__ wv, short* __restrict__ wt2) {
  int idx = blockIdx.x * 256 + threadIdx.x;   // 0 .. 3*65536-1
  int m = idx >> 16;
  int f = idx & 65535;
  int k0g = f >> 11, hc = (f >> 9) & 3, lr = (f >> 5) & 15, lg = (f >> 3) & 3, j = f & 7;
  int c = k0g * 32 + lg * 8 + j, h = hc * 16 + lr;
  const float* w = (m == 0) ? wq : (m == 1) ? wk : wv;
  wt2[((k0g * 12 + m * 4 + hc) * 64 + lr * 4 + lg) * 8 + j] = f2bf(w[c * 64 + h]);
}

// ---------------- kernel 1: fused q/k/v projection ----------------
__global__ __launch_bounds__(512) void proj_kernel(const float* __restrict__ x,
                                                   const short* __restrict__ wt2,
                                                   short* __restrict__ ws) {
  __shared__ short xs[2][1024];
  __shared__ short vt_lds[8][16][24];

  int tid = threadIdx.x;
  int widx = tid >> 6, lane = tid & 63;
  int lr = lane & 15, lg = lane >> 4;
  int row0 = blockIdx.x * 32;
  int rbh = widx >> 2;
  int hcw = widx & 3;

  int srow = tid >> 4, sc2 = tid & 15;
  const float* xsrc = x + (size_t)(row0 + srow) * CDIM + sc2 * 2;
  int sdst = (srow >> 4) * 512 + (srow & 15) * 32 + (sc2 >> 2) * 8 + (sc2 & 3) * 2;

  const short* xrd  = &xs[0][0] + rbh * 512 + (lr * 4 + lg) * 8;
  const short* bptr = wt2 + (hcw * 64 + lr * 4 + lg) * 8;

  f32x4 acc[3] = {};

#define LDX(K)  (*(const float2*)(xsrc + (K) * 32))
#define STAGE(A, BUF) do {                                                   \
    unsigned u_ = (unsigned)(unsigned short)f2bf((A).x) |                    \
                  ((unsigned)(unsigned short)f2bf((A).y) << 16);             \
    *(unsigned*)(&xs[(BUF)][sdst]) = u_;                                     \
  } while (0)
#define COMPUTE(BUF, K) do {                                                 \
    bf16x8 af_ = *(const bf16x8*)(xrd + (BUF) * 1024);                       \
    const short* bk_ = bptr + (K) * (12 * 512);                              \
    _Pragma("unroll")                                                        \
    for (int pp = 0; pp < 3; ++pp) {                                         \
      bf16x8 bf_ = ld8(bk_ + pp * 2048);                                     \
      acc[pp] = __builtin_amdgcn_mfma_f32_16x16x32_bf16(af_, bf_, acc[pp], 0, 0, 0); \
    }                                                                        \
  } while (0)

  float2 a1 = LDX(1);
  { float2 a0 = LDX(0); STAGE(a0, 0); }
  __syncthreads();

  for (int k = 0; k < 32; k += 2) {
    float2 an0 = {0.f, 0.f}, an1 = {0.f, 0.f};
    if (k + 2 < 32) an0 = LDX(k + 2);
    COMPUTE(0, k);
    STAGE(a1, 1);
    __syncthreads();
    if (k + 2 < 32) an1 = LDX(k + 3);
    COMPUTE(1, k + 1);
    if (k + 2 < 32) STAGE(an0, 0);
    __syncthreads();
    a1 = an1;
  }

  short* qs  = ws + Q_OFF;
  short* kst = ws + K_OFF;
  short* vts = ws + VT_OFF;
  int rbase = row0 + rbh * 16;
#pragma unroll
  for (int reg = 0; reg < 4; ++reg) {
    int t = rbase + lg * 4 + reg;
    qs [t * 64 + hcw * 16 + lr] = f2bf(acc[0][reg]);
    kst[t * 64 + hcw * 16 + lr] = f2bf(acc[1][reg]);
    vt_lds[widx][lr][lg * 4 + reg] = f2bf(acc[2][reg]);
  }
  if (lane < 32) {
    int hl = lane >> 1, tf = (lane & 1) * 8;
    bf16x8 vv = *(const bf16x8*)(&vt_lds[widx][hl][tf]);
    int bb = rbase >> 12, tt0 = rbase & (SEQ - 1);
    *(bf16x8*)(vts + (size_t)(bb * 64 + hcw * 16 + hl) * SEQ + tt0 + tf) = vv;
  }
}

// ---------------- kernel 2: causal flash attention (no-max softmax) ----------
// block = 1 q-tile (16 rows), 4 waves split KV 4-way, KVBLK=64; plain-sum merge.
__global__ __launch_bounds__(256) void attn_kernel(const short* __restrict__ ws,
                                                   float* __restrict__ out) {
  __shared__ float p_o[4][4][4][64];    // 16KB
  __shared__ float p_l[4][4][64];       // 4KB
  __shared__ short plds[4][16][72];     // 9KB

  int widx = threadIdx.x >> 6, lane = threadIdx.x & 63;
  int lr = lane & 15, lg = lane >> 4;
  int g = blockIdx.x;
  int b = g >> 8, qt = 255 - (g & 255);   // heavy-first

  const short* qs  = ws + Q_OFF;
  const short* kst = ws + K_OFF;
  const short* vts = ws + VT_OFF;

  int qbase = b * SEQ + qt * 16;
  bf16x8 qf0 = ld8(qs + (qbase + lr) * 64 + lg * 8);
  bf16x8 qf1 = ld8(qs + (qbase + lr) * 64 + 32 + lg * 8);

  f32x4 o[4] = {};
  float l_run[4] = {};
  short* myp = &plds[widx][0][0];
  int nkv = (qt >> 2) + 1;   // # of 64-wide kv blocks

  for (int kvb = widx; kvb < nkv; kvb += 4) {
    int kv0 = kvb * 64;
    const short* kb = kst + (b * SEQ + kv0) * 64;

    f32x4 s[4] = {};
#pragma unroll
    for (int st = 0; st < 4; ++st) {
      s[st] = __builtin_amdgcn_mfma_f32_16x16x32_bf16(qf0, ld8(kb + (st * 16 + lr) * 64 + lg * 8), s[st], 0, 0, 0);
      s[st] = __builtin_amdgcn_mfma_f32_16x16x32_bf16(qf1, ld8(kb + (st * 16 + lr) * 64 + 32 + lg * 8), s[st], 0, 0, 0);
    }

    // prefetch V fragments (latency hides under P's LDS roundtrip)
    const short* vb = vts + b * 64 * SEQ + kv0;
    bf16x8 vf0[4], vf1[4];
#pragma unroll
    for (int hc = 0; hc < 4; ++hc) {
      vf0[hc] = ld8(vb + (hc * 16 + lr) * SEQ + lg * 8);
      vf1[hc] = ld8(vb + (hc * 16 + lr) * SEQ + 32 + lg * 8);
    }

    bool last = (kvb == nkv - 1);
    // no-max softmax: P = exp(s/8); l accumulates in-lane (no cross-lane ops)
#pragma unroll
    for (int reg = 0; reg < 4; ++reg) {
      int ig = qt * 16 + lg * 4 + reg;
#pragma unroll
      for (int st = 0; st < 4; ++st) {
        float v = s[st][reg] * 0.125f;
        if (last && (kv0 + st * 16 + lr > ig)) v = -1e30f;
        float p = __expf(v);
        l_run[reg] += p;
        myp[(lg * 4 + reg) * 72 + st * 16 + lr] = f2bf(p);
      }
    }
    asm volatile("s_waitcnt lgkmcnt(0)" ::: "memory");
    bf16x8 pf0 = ld8(myp + lr * 72 + lg * 8);
    bf16x8 pf1 = ld8(myp + lr * 72 + 32 + lg * 8);

#pragma unroll
    for (int hc = 0; hc < 4; ++hc) {
      o[hc] = __builtin_amdgcn_mfma_f32_16x16x32_bf16(pf0, vf0[hc], o[hc], 0, 0, 0);
      o[hc] = __builtin_amdgcn_mfma_f32_16x16x32_bf16(pf1, vf1[hc], o[hc], 0, 0, 0);
    }
  }

  // one-time cross-lane reduce of l (row sum over the 16 kv-lanes)
#pragma unroll
  for (int reg = 0; reg < 4; ++reg) {
    float l = l_run[reg];
    l += __shfl_xor(l, 1);
    l += __shfl_xor(l, 2);
    l += __shfl_xor(l, 4);
    l += __shfl_xor(l, 8);
    l_run[reg] = l;
  }

  // publish partials
#pragma unroll
  for (int hc = 0; hc < 4; ++hc)
#pragma unroll
    for (int reg = 0; reg < 4; ++reg)
      p_o[widx][hc][reg][lane] = o[hc][reg];
#pragma unroll
  for (int reg = 0; reg < 4; ++reg)
    p_l[widx][reg][lane] = l_run[reg];
  __syncthreads();

  // merge: wave w handles reg = w (plain sums — softmax shift-invariant)
  {
    int reg = widx;
    float lsum = p_l[0][reg][lane] + p_l[1][reg][lane] +
                 p_l[2][reg][lane] + p_l[3][reg][lane];
    float inv = 1.0f / lsum;
#pragma unroll
    for (int hc = 0; hc < 4; ++hc) {
      float s = p_o[0][hc][reg][lane] + p_o[1][hc][reg][lane] +
                p_o[2][hc][reg][lane] + p_o[3][hc][reg][lane];
      out[(qbase + lg * 4 + reg) * 64 + hc * 16 + lr] = s * inv;
    }
  }
}

extern "C" void kernel_launch(void* const* d_in, const int* in_sizes, int n_in,
                              void* d_out, int out_size, void* d_ws, size_t ws_size,
                              hipStream_t stream) {
  const float* x  = (const float*)d_in[0];
  const float* wq = (const float*)d_in[1];
  const float* wk = (const float*)d_in[2];
  const float* wv = (const float*)d_in[3];
  short* ws = (short*)d_ws;
  float* out = (float*)d_out;

  wcvt_kernel<<<dim3(768), dim3(256), 0, stream>>>(wq, wk, wv, ws + WT_OFF);
  proj_kernel<<<dim3(512), dim3(512), 0, stream>>>(x, ws + WT_OFF, ws);
  attn_kernel<<<dim3(1024), dim3(256), 0, stream>>>(ws, out);
}

// Round 5
// 99.581 us; speedup vs baseline: 1.5150x; 1.5150x over previous
//
#include <hip/hip_runtime.h>

#define BATCH 4
#define SEQ   4096
#define CDIM  1024
#define HDIM  64

typedef __attribute__((ext_vector_type(8))) short bf16x8;
typedef __attribute__((ext_vector_type(4))) float f32x4;

// ws layout (in shorts):
//   wt2 [32 k0g][12 p=m*4+hc][64 lane][8]  (bf16, MFMA-fragment order) @ 0
//   q   [16384][64]   (bf16, row-major)   @ Q_OFF
//   k   [16384][64]   (bf16, row-major)   @ K_OFF
//   vt  [4][64][4096] (bf16, transposed)  @ VT_OFF
#define WT_OFF 0
#define Q_OFF  (3 * HDIM * CDIM)
#define K_OFF  (Q_OFF + BATCH * SEQ * HDIM)
#define VT_OFF (K_OFF + BATCH * SEQ * HDIM)

static __device__ __forceinline__ short f2bf(float f) {
  union { float f; unsigned u; } a; a.f = f;
  unsigned r = a.u + 0x7fffu + ((a.u >> 16) & 1u);   // RNE
  return (short)(r >> 16);
}

static __device__ __forceinline__ bf16x8 ld8(const short* p) {
  return *(const bf16x8*)p;
}

// ---------------- kernel 0: W -> bf16, MFMA-fragment order ----------------
__global__ void wcvt_kernel(const float* __restrict__ wq, const float* __restrict__ wk,
                            const float* __restrict__ wv, short* __restrict__ wt2) {
  int idx = blockIdx.x * 256 + threadIdx.x;   // 0 .. 3*65536-1
  int m = idx >> 16;
  int f = idx & 65535;
  int k0g = f >> 11, hc = (f >> 9) & 3, lr = (f >> 5) & 15, lg = (f >> 3) & 3, j = f & 7;
  int c = k0g * 32 + lg * 8 + j, h = hc * 16 + lr;
  const float* w = (m == 0) ? wq : (m == 1) ? wk : wv;
  wt2[((k0g * 12 + m * 4 + hc) * 64 + lr * 4 + lg) * 8 + j] = f2bf(w[c * 64 + h]);
}

// ---------------- kernel 1: fused q/k/v projection ----------------
__global__ __launch_bounds__(512) void proj_kernel(const float* __restrict__ x,
                                                   const short* __restrict__ wt2,
                                                   short* __restrict__ ws) {
  __shared__ short xs[2][1024];
  __shared__ short vt_lds[8][16][24];

  int tid = threadIdx.x;
  int widx = tid >> 6, lane = tid & 63;
  int lr = lane & 15, lg = lane >> 4;
  int row0 = blockIdx.x * 32;
  int rbh = widx >> 2;
  int hcw = widx & 3;

  int srow = tid >> 4, sc2 = tid & 15;
  const float* xsrc = x + (size_t)(row0 + srow) * CDIM + sc2 * 2;
  int sdst = (srow >> 4) * 512 + (srow & 15) * 32 + (sc2 >> 2) * 8 + (sc2 & 3) * 2;

  const short* xrd  = &xs[0][0] + rbh * 512 + (lr * 4 + lg) * 8;
  const short* bptr = wt2 + (hcw * 64 + lr * 4 + lg) * 8;

  f32x4 acc[3] = {};

#define LDX(K)  (*(const float2*)(xsrc + (K) * 32))
#define STAGE(A, BUF) do {                                                   \
    unsigned u_ = (unsigned)(unsigned short)f2bf((A).x) |                    \
                  ((unsigned)(unsigned short)f2bf((A).y) << 16);             \
    *(unsigned*)(&xs[(BUF)][sdst]) = u_;                                     \
  } while (0)
#define COMPUTE(BUF, K) do {                                                 \
    bf16x8 af_ = *(const bf16x8*)(xrd + (BUF) * 1024);                       \
    const short* bk_ = bptr + (K) * (12 * 512);                              \
    _Pragma("unroll")                                                        \
    for (int pp = 0; pp < 3; ++pp) {                                         \
      bf16x8 bf_ = ld8(bk_ + pp * 2048);                                     \
      acc[pp] = __builtin_amdgcn_mfma_f32_16x16x32_bf16(af_, bf_, acc[pp], 0, 0, 0); \
    }                                                                        \
  } while (0)

  float2 a1 = LDX(1);
  { float2 a0 = LDX(0); STAGE(a0, 0); }
  __syncthreads();

  for (int k = 0; k < 32; k += 2) {
    float2 an0 = {0.f, 0.f}, an1 = {0.f, 0.f};
    if (k + 2 < 32) an0 = LDX(k + 2);
    COMPUTE(0, k);
    STAGE(a1, 1);
    __syncthreads();
    if (k + 2 < 32) an1 = LDX(k + 3);
    COMPUTE(1, k + 1);
    if (k + 2 < 32) STAGE(an0, 0);
    __syncthreads();
    a1 = an1;
  }

  short* qs  = ws + Q_OFF;
  short* kst = ws + K_OFF;
  short* vts = ws + VT_OFF;
  int rbase = row0 + rbh * 16;
#pragma unroll
  for (int reg = 0; reg < 4; ++reg) {
    int t = rbase + lg * 4 + reg;
    qs [t * 64 + hcw * 16 + lr] = f2bf(acc[0][reg]);
    kst[t * 64 + hcw * 16 + lr] = f2bf(acc[1][reg]);
    vt_lds[widx][lr][lg * 4 + reg] = f2bf(acc[2][reg]);
  }
  if (lane < 32) {
    int hl = lane >> 1, tf = (lane & 1) * 8;
    bf16x8 vv = *(const bf16x8*)(&vt_lds[widx][hl][tf]);
    int bb = rbase >> 12, tt0 = rbase & (SEQ - 1);
    *(bf16x8*)(vts + (size_t)(bb * 64 + hcw * 16 + hl) * SEQ + tt0 + tf) = vv;
  }
}

// ---------------- kernel 2: causal flash attention (no-max softmax) ----------
// 512 blocks x 512 thr; block = 32 q-rows; wave = (rt = widx>>2, kl = widx&3);
// per-CU balanced: blocks c and c+256 share batch, t32 sums to 127.
__global__ __launch_bounds__(512) void attn_kernel(const short* __restrict__ ws,
                                                   float* __restrict__ out) {
  __shared__ float p_o[8][4][4][64];    // 32KB
  __shared__ float p_l[8][4][64];       // 8KB
  __shared__ short plds[8][16][72];     // 18KB

  int widx = threadIdx.x >> 6, lane = threadIdx.x & 63;
  int lr = lane & 15, lg = lane >> 4;
  int rt = widx >> 2, kl = widx & 3;

  int g = blockIdx.x;
  int i = g & 255, hi = g >> 8;
  int b = i & 3;
  int t32 = hi ? 127 - (i >> 2) : (i >> 2);

  const short* qs  = ws + Q_OFF;
  const short* kst = ws + K_OFF;
  const short* vts = ws + VT_OFF;

  int qrow0 = b * SEQ + t32 * 32 + rt * 16;       // this wave's 16 rows
  bf16x8 qf0 = ld8(qs + (qrow0 + lr) * 64 + lg * 8);
  bf16x8 qf1 = ld8(qs + (qrow0 + lr) * 64 + 32 + lg * 8);

  const short* kbb = kst + b * SEQ * 64;
  const short* vbb = vts + b * 64 * SEQ;

  f32x4 o[4] = {};
  float l_run[4] = {};
  short* myp = &plds[widx][0][0];
  int nkv = (t32 >> 1) + 1;    // # of 64-wide kv blocks for this tile

  bf16x8 kf[8];
  int kvb = kl;
  if (kvb < nkv) {
    const short* kb = kbb + kvb * 64 * 64;
#pragma unroll
    for (int st = 0; st < 4; ++st) {
      kf[st * 2]     = ld8(kb + (st * 16 + lr) * 64 + lg * 8);
      kf[st * 2 + 1] = ld8(kb + (st * 16 + lr) * 64 + 32 + lg * 8);
    }
  }

  for (; kvb < nkv; kvb += 4) {
    int kv0 = kvb * 64;

    f32x4 s[4] = {};
#pragma unroll
    for (int st = 0; st < 4; ++st) {
      s[st] = __builtin_amdgcn_mfma_f32_16x16x32_bf16(qf0, kf[st * 2],     s[st], 0, 0, 0);
      s[st] = __builtin_amdgcn_mfma_f32_16x16x32_bf16(qf1, kf[st * 2 + 1], s[st], 0, 0, 0);
    }

    // prefetch V fragments (latency hides under exp + LDS roundtrip)
    bf16x8 vf[8];
    const short* vb = vbb + kv0;
#pragma unroll
    for (int hc = 0; hc < 4; ++hc) {
      vf[hc * 2]     = ld8(vb + (hc * 16 + lr) * SEQ + lg * 8);
      vf[hc * 2 + 1] = ld8(vb + (hc * 16 + lr) * SEQ + 32 + lg * 8);
    }
    // prefetch next K block (hides K latency under this iteration's tail)
    int kvn = kvb + 4;
    if (kvn < nkv) {
      const short* kb = kbb + kvn * 64 * 64;
#pragma unroll
      for (int st = 0; st < 4; ++st) {
        kf[st * 2]     = ld8(kb + (st * 16 + lr) * 64 + lg * 8);
        kf[st * 2 + 1] = ld8(kb + (st * 16 + lr) * 64 + 32 + lg * 8);
      }
    }

    bool last = (kvb == nkv - 1);
#pragma unroll
    for (int reg = 0; reg < 4; ++reg) {
      int ig = t32 * 32 + rt * 16 + lg * 4 + reg;
#pragma unroll
      for (int st = 0; st < 4; ++st) {
        float v = s[st][reg] * 0.125f;
        if (last && (kv0 + st * 16 + lr > ig)) v = -1e30f;
        float p = __expf(v);
        l_run[reg] += p;
        myp[(lg * 4 + reg) * 72 + st * 16 + lr] = f2bf(p);
      }
    }
    asm volatile("s_waitcnt lgkmcnt(0)" ::: "memory");
    bf16x8 pf0 = ld8(myp + lr * 72 + lg * 8);
    bf16x8 pf1 = ld8(myp + lr * 72 + 32 + lg * 8);

#pragma unroll
    for (int hc = 0; hc < 4; ++hc) {
      o[hc] = __builtin_amdgcn_mfma_f32_16x16x32_bf16(pf0, vf[hc * 2],     o[hc], 0, 0, 0);
      o[hc] = __builtin_amdgcn_mfma_f32_16x16x32_bf16(pf1, vf[hc * 2 + 1], o[hc], 0, 0, 0);
    }
  }

  // in-lane l -> row sum (one-time)
#pragma unroll
  for (int reg = 0; reg < 4; ++reg) {
    float l = l_run[reg];
    l += __shfl_xor(l, 1);
    l += __shfl_xor(l, 2);
    l += __shfl_xor(l, 4);
    l += __shfl_xor(l, 8);
    l_run[reg] = l;
  }

  // publish partials
#pragma unroll
  for (int hc = 0; hc < 4; ++hc)
#pragma unroll
    for (int reg = 0; reg < 4; ++reg)
      p_o[widx][hc][reg][lane] = o[hc][reg];
#pragma unroll
  for (int reg = 0; reg < 4; ++reg)
    p_l[widx][reg][lane] = l_run[reg];
  __syncthreads();

  // merge: wave widx -> (mrt = widx>>2, mhc = widx&3); plain sums over kl
  {
    int mrt = widx >> 2, mhc = widx & 3;
    int obase = b * SEQ + t32 * 32 + mrt * 16;
#pragma unroll
    for (int reg = 0; reg < 4; ++reg) {
      float lsum = p_l[mrt * 4 + 0][reg][lane] + p_l[mrt * 4 + 1][reg][lane] +
                   p_l[mrt * 4 + 2][reg][lane] + p_l[mrt * 4 + 3][reg][lane];
      float inv = 1.0f / lsum;
      float sv = p_o[mrt * 4 + 0][mhc][reg][lane] + p_o[mrt * 4 + 1][mhc][reg][lane] +
                 p_o[mrt * 4 + 2][mhc][reg][lane] + p_o[mrt * 4 + 3][mhc][reg][lane];
      out[(obase + lg * 4 + reg) * 64 + mhc * 16 + lr] = sv * inv;
    }
  }
}

extern "C" void kernel_launch(void* const* d_in, const int* in_sizes, int n_in,
                              void* d_out, int out_size, void* d_ws, size_t ws_size,
                              hipStream_t stream) {
  const float* x  = (const float*)d_in[0];
  const float* wq = (const float*)d_in[1];
  const float* wk = (const float*)d_in[2];
  const float* wv = (const float*)d_in[3];
  short* ws = (short*)d_ws;
  float* out = (float*)d_out;

  wcvt_kernel<<<dim3(768), dim3(256), 0, stream>>>(wq, wk, wv, ws + WT_OFF);
  proj_kernel<<<dim3(512), dim3(512), 0, stream>>>(x, ws + WT_OFF, ws);
  attn_kernel<<<dim3(512), dim3(512), 0, stream>>>(ws, out);
}

// Round 7
// 65.250 us; speedup vs baseline: 2.3121x; 1.5261x over previous
//
#include <hip/hip_runtime.h>

#define BATCH 4
#define SEQ   4096
#define CDIM  1024
#define HDIM  64

typedef __attribute__((ext_vector_type(8))) short bf16x8;
typedef __attribute__((ext_vector_type(4))) float f32x4;

// ws layout (in shorts):
//   wt2   [32 k0g][12 p][64 lane][8]            (bf16, frag order) @ 0
//   q     [16384][64]   (bf16, row-major)       @ Q_OFF
//   kfrag [4][64 kb64][4 st][2 half][512]       @ KF_OFF  (attn B-op for QK^T)
//   vfrag [4][64 kb64][2 half][4 hc][512]       @ VF_OFF  (attn B-op for PV)
//   fragment interior layout: [lg][lr][j] = lg*128 + lr*8 + j  (lane*8+j)
#define WT_OFF 0
#define Q_OFF  (3 * HDIM * CDIM)
#define KF_OFF (Q_OFF + BATCH * SEQ * HDIM)
#define VF_OFF (KF_OFF + BATCH * SEQ * HDIM)

static __device__ __forceinline__ short f2bf(float f) {
  union { float f; unsigned u; } a; a.f = f;
  unsigned r = a.u + 0x7fffu + ((a.u >> 16) & 1u);   // RNE
  return (short)(r >> 16);
}

static __device__ __forceinline__ bf16x8 ld8(const short* p) {
  return *(const bf16x8*)p;
}

// ---------------- kernel 0: W -> bf16, MFMA-fragment order ----------------
__global__ void wcvt_kernel(const float* __restrict__ wq, const float* __restrict__ wk,
                            const float* __restrict__ wv, short* __restrict__ wt2) {
  int idx = blockIdx.x * 256 + threadIdx.x;   // 0 .. 3*65536-1
  int m = idx >> 16;
  int f = idx & 65535;
  int k0g = f >> 11, hc = (f >> 9) & 3, lr = (f >> 5) & 15, lg = (f >> 3) & 3, j = f & 7;
  int c = k0g * 32 + lg * 8 + j, h = hc * 16 + lr;
  const float* w = (m == 0) ? wq : (m == 1) ? wk : wv;
  wt2[((k0g * 12 + m * 4 + hc) * 64 + lr * 4 + lg) * 8 + j] = f2bf(w[c * 64 + h]);
}

// ---------------- kernel 1: fused q/k/v projection ----------------
// block = 32 rows, 8 waves; x staged in LDS double-buffered; K/V reshaped to
// MFMA fragment order via per-wave LDS transpose.
__global__ __launch_bounds__(512) void proj_kernel(const float* __restrict__ x,
                                                   const short* __restrict__ wt2,
                                                   short* __restrict__ ws) {
  __shared__ short xs[2][1024];
  __shared__ short k_lds[8][16][24];     // [wave][t16][h16]
  __shared__ short v_lds[8][16][24];     // [wave][h16][t16]

  int tid = threadIdx.x;
  int widx = tid >> 6, lane = tid & 63;
  int lr = lane & 15, lg = lane >> 4;
  int row0 = blockIdx.x * 32;
  int rbh = widx >> 2;
  int hcw = widx & 3;

  int srow = tid >> 4, sc2 = tid & 15;
  const float* xsrc = x + (size_t)(row0 + srow) * CDIM + sc2 * 2;
  int sdst = (srow >> 4) * 512 + (srow & 15) * 32 + (sc2 >> 2) * 8 + (sc2 & 3) * 2;

  const short* xrd  = &xs[0][0] + rbh * 512 + (lr * 4 + lg) * 8;
  const short* bptr = wt2 + (hcw * 64 + lr * 4 + lg) * 8;

  f32x4 acc[3] = {};

#define LDX(K)  (*(const float2*)(xsrc + (K) * 32))
#define STAGE(A, BUF) do {                                                   \
    unsigned u_ = (unsigned)(unsigned short)f2bf((A).x) |                    \
                  ((unsigned)(unsigned short)f2bf((A).y) << 16);             \
    *(unsigned*)(&xs[(BUF)][sdst]) = u_;                                     \
  } while (0)
#define COMPUTE(BUF, K) do {                                                 \
    bf16x8 af_ = *(const bf16x8*)(xrd + (BUF) * 1024);                       \
    const short* bk_ = bptr + (K) * (12 * 512);                              \
    _Pragma("unroll")                                                        \
    for (int pp = 0; pp < 3; ++pp) {                                         \
      bf16x8 bf_ = ld8(bk_ + pp * 2048);                                     \
      acc[pp] = __builtin_amdgcn_mfma_f32_16x16x32_bf16(af_, bf_, acc[pp], 0, 0, 0); \
    }                                                                        \
  } while (0)

  float2 a1 = LDX(1);
  { float2 a0 = LDX(0); STAGE(a0, 0); }
  __syncthreads();

  for (int k = 0; k < 32; k += 2) {
    float2 an0 = {0.f, 0.f}, an1 = {0.f, 0.f};
    if (k + 2 < 32) an0 = LDX(k + 2);
    COMPUTE(0, k);
    STAGE(a1, 1);
    __syncthreads();
    if (k + 2 < 32) an1 = LDX(k + 3);
    COMPUTE(1, k + 1);
    if (k + 2 < 32) STAGE(an0, 0);
    __syncthreads();
    a1 = an1;
  }

  short* qs  = ws + Q_OFF;
  short* kfr = ws + KF_OFF;
  short* vfr = ws + VF_OFF;
  int rbase = row0 + rbh * 16;           // 16-aligned
#pragma unroll
  for (int reg = 0; reg < 4; ++reg) {
    int t = rbase + lg * 4 + reg;
    qs[t * 64 + hcw * 16 + lr] = f2bf(acc[0][reg]);
    k_lds[widx][lg * 4 + reg][lr] = f2bf(acc[1][reg]);   // [t16][h16]
    v_lds[widx][lr][lg * 4 + reg] = f2bf(acc[2][reg]);   // [h16][t16]
  }
  // fragment-order stores; fragment interior = lane*8+j with lane = lg*16+lr
  int b = rbase >> 12;
  int tb = rbase & (SEQ - 1);
  int kb64 = tb >> 6, st = (tb >> 4) & 3;
  if (lane < 32) {
    int i0 = lane >> 1, f8 = (lane & 1) * 8;
    // K frag: value K[rbase+i0][hcw*16+f8+j] -> lr=i0, half=hcw>>1,
    //         lg=(hcw&1)*2+(f8>>3)
    size_t kblk = ((((size_t)b * 64 + kb64) * 4 + st) * 2 + (hcw >> 1)) * 512;
    bf16x8 kv8 = *(const bf16x8*)(&k_lds[widx][i0][f8]);
    *(bf16x8*)(kfr + kblk + ((hcw & 1) * 2 + (f8 >> 3)) * 128 + i0 * 8) = kv8;
    // V frag: value V[rbase+f8+j][hcw*16+i0] -> lr=i0, half=(tb>>5)&1,
    //         lg=((tb&16)+f8)>>3
    size_t vblk = ((((size_t)b * 64 + kb64) * 2 + ((tb >> 5) & 1)) * 4 + hcw) * 512;
    bf16x8 vv8 = *(const bf16x8*)(&v_lds[widx][i0][f8]);
    *(bf16x8*)(vfr + vblk + (((tb & 16) + f8) >> 3) * 128 + i0 * 8) = vv8;
  }
}

// ---------------- kernel 2: causal flash attention (no-max softmax) ----------
// 512 blocks x 512 thr; block g processes 16-row tiles g and 1023-g
// (heavy-first ordering -> per-block work constant). 8 waves split KV 8-way.
__global__ __launch_bounds__(512, 4) void attn_kernel(const short* __restrict__ ws,
                                                      float* __restrict__ out) {
  __shared__ float p_o[8][4][4][64];    // 32KB
  __shared__ float p_l[8][4][64];       // 8KB
  __shared__ short plds[8][16][72];     // 18KB

  int widx = threadIdx.x >> 6, lane = threadIdx.x & 63;
  int lr = lane & 15, lg = lane >> 4;
  int g = blockIdx.x;

  const short* qs  = ws + Q_OFF;
  const short* kfr = ws + KF_OFF;
  const short* vfr = ws + VF_OFF;
  short* myp = &plds[widx][0][0];

  for (int tt = 0; tt < 2; ++tt) {
    int j = tt == 0 ? g : 1023 - g;
    int t16 = 255 - (j >> 2), b = j & 3;     // heavy-first tile ordering
    int qrow0 = b * SEQ + t16 * 16;
    int nkv = (t16 >> 2) + 1;                // # of 64-wide kv blocks

    bf16x8 qf0 = ld8(qs + (qrow0 + lr) * 64 + lg * 8);
    bf16x8 qf1 = ld8(qs + (qrow0 + lr) * 64 + 32 + lg * 8);
    const short* kb_b = kfr + (size_t)b * 64 * 4096 + lane * 8;
    const short* vb_b = vfr + (size_t)b * 64 * 4096 + lane * 8;

    f32x4 o[4] = {};
    float l_run[4] = {};

    if (tt) __syncthreads();   // guard LDS reuse across tiles

    bf16x8 kf[8];
    int kvb = widx;
    if (kvb < nkv) {
      const short* kb = kb_b + (size_t)kvb * 4096;
#pragma unroll
      for (int q8 = 0; q8 < 8; ++q8) kf[q8] = ld8(kb + q8 * 512);
    }

    for (; kvb < nkv; kvb += 8) {
      int kv0 = kvb * 64;

      f32x4 s[4] = {};
#pragma unroll
      for (int st = 0; st < 4; ++st) {
        s[st] = __builtin_amdgcn_mfma_f32_16x16x32_bf16(qf0, kf[st * 2],     s[st], 0, 0, 0);
        s[st] = __builtin_amdgcn_mfma_f32_16x16x32_bf16(qf1, kf[st * 2 + 1], s[st], 0, 0, 0);
      }

      // V fragments: coalesced 1KB loads; latency hides under exp+LDS roundtrip
      bf16x8 vv[8];
      {
        const short* vb = vb_b + (size_t)kvb * 4096;
#pragma unroll
        for (int q8 = 0; q8 < 8; ++q8) vv[q8] = ld8(vb + q8 * 512);
      }
      // prefetch next K block
      int kvn = kvb + 8;
      if (kvn < nkv) {
        const short* kb = kb_b + (size_t)kvn * 4096;
#pragma unroll
        for (int q8 = 0; q8 < 8; ++q8) kf[q8] = ld8(kb + q8 * 512);
      }

      bool last = (kvb == nkv - 1);
#pragma unroll
      for (int reg = 0; reg < 4; ++reg) {
        int ig = t16 * 16 + lg * 4 + reg;
#pragma unroll
        for (int st = 0; st < 4; ++st) {
          float v = s[st][reg] * 0.125f;
          if (last && (kv0 + st * 16 + lr > ig)) v = -1e30f;
          float p = __expf(v);
          l_run[reg] += p;
          myp[(lg * 4 + reg) * 72 + st * 16 + lr] = f2bf(p);
        }
      }
      asm volatile("s_waitcnt lgkmcnt(0)" ::: "memory");
      bf16x8 pf0 = ld8(myp + lr * 72 + lg * 8);
      bf16x8 pf1 = ld8(myp + lr * 72 + 32 + lg * 8);

#pragma unroll
      for (int hc = 0; hc < 4; ++hc) {
        o[hc] = __builtin_amdgcn_mfma_f32_16x16x32_bf16(pf0, vv[hc],     o[hc], 0, 0, 0);
        o[hc] = __builtin_amdgcn_mfma_f32_16x16x32_bf16(pf1, vv[4 + hc], o[hc], 0, 0, 0);
      }
    }

    // in-lane l -> row sum
#pragma unroll
    for (int reg = 0; reg < 4; ++reg) {
      float l = l_run[reg];
      l += __shfl_xor(l, 1);
      l += __shfl_xor(l, 2);
      l += __shfl_xor(l, 4);
      l += __shfl_xor(l, 8);
      l_run[reg] = l;
    }

    // publish partials
#pragma unroll
    for (int hc = 0; hc < 4; ++hc)
#pragma unroll
      for (int reg = 0; reg < 4; ++reg)
        p_o[widx][hc][reg][lane] = o[hc][reg];
#pragma unroll
    for (int reg = 0; reg < 4; ++reg)
      p_l[widx][reg][lane] = l_run[reg];
    __syncthreads();

    // merge: waves 0-3 handle reg = widx; plain sums (no-max softmax)
    if (widx < 4) {
      int reg = widx;
      float lsum = 0.f;
#pragma unroll
      for (int w = 0; w < 8; ++w) lsum += p_l[w][reg][lane];
      float inv = 1.0f / lsum;
#pragma unroll
      for (int hc = 0; hc < 4; ++hc) {
        float sv = 0.f;
#pragma unroll
        for (int w = 0; w < 8; ++w) sv += p_o[w][hc][reg][lane];
        out[(qrow0 + lg * 4 + reg) * 64 + hc * 16 + lr] = sv * inv;
      }
    }
  }
}

extern "C" void kernel_launch(void* const* d_in, const int* in_sizes, int n_in,
                              void* d_out, int out_size, void* d_ws, size_t ws_size,
                              hipStream_t stream) {
  const float* x  = (const float*)d_in[0];
  const float* wq = (const float*)d_in[1];
  const float* wk = (const float*)d_in[2];
  const float* wv = (const float*)d_in[3];
  short* ws = (short*)d_ws;
  float* out = (float*)d_out;

  wcvt_kernel<<<dim3(768), dim3(256), 0, stream>>>(wq, wk, wv, ws + WT_OFF);
  proj_kernel<<<dim3(512), dim3(512), 0, stream>>>(x, ws + WT_OFF, ws);
  attn_kernel<<<dim3(512), dim3(512), 0, stream>>>(ws, out);
}